// Round 14
// baseline (689.889 us; speedup 1.0000x reference)
//
#include <hip/hip_runtime.h>
#include <stdint.h>
#include <math.h>

#define SB 256
#define SI 8
#define SCHUNK (SB*SI)
#define C2 2048            // occurrence-key chunk per block
#define LDSN (C2 + 256)    // + margin for the boundary bucket (max bucket ~74)
#define HEADBIT 0x40000000u
#define VMASK   0x3FFFFFFFu
#define NXCD 8
#define SLOTMASK 0x1fffu   // 13-bit per-XCD slot; xcd in bits 13..15

__constant__ int c_tri[16][6] = {
  {-1,-1,-1,-1,-1,-1},{1,0,2,-1,-1,-1},{4,0,3,-1,-1,-1},{1,4,2,1,3,4},
  {3,1,5,-1,-1,-1},{2,3,0,2,5,3},{1,4,0,1,5,4},{4,2,5,-1,-1,-1},
  {4,5,2,-1,-1,-1},{4,1,0,4,5,1},{3,2,0,3,5,2},{1,3,5,-1,-1,-1},
  {4,1,2,4,3,1},{3,0,4,-1,-1,-1},{2,0,1,-1,-1,-1},{-1,-1,-1,-1,-1,-1}};
__constant__ int c_ntri[16] = {0,1,1,2,1,2,2,1,1,2,2,1,2,1,1,0};
__constant__ int c_ea[6] = {0,0,0,1,1,2};
__constant__ int c_eb[6] = {1,2,3,2,3,3};

// ---------------- classify: XCD-local (L2-resolved) bucket counting -----------
// Device-scope atomics bypass L2 (r10/r11: WRITE_SIZE tracks atomic count at
// ~25G/s). Fix: per-XCD count slices + workgroup-scope atomics -> resolved in
// the XCD's own L2. One atomic per DISTINCT lo within the tet. Slot =
// (xcd<<13)|local_slot; rank-by-counting later canonicalizes any ordering.
__global__ void k_classify(const int4* __restrict__ tet, const float* __restrict__ sdf,
                           uint8_t* __restrict__ tetidx, int* __restrict__ xoff,
                           ushort4* __restrict__ stash, int nt, int nv) {
  unsigned xcc;
  asm volatile("s_getreg_b32 %0, hwreg(HW_REG_XCC_ID)" : "=s"(xcc));
  xcc &= 7;
  int* myCnt = xoff + (size_t)xcc * nv;
  int t = blockIdx.x * blockDim.x + threadIdx.x;
  if (t >= nt) return;
  int4 v = tet[t];
  int ids[4] = {v.x, v.y, v.z, v.w};
  int bits = 0;
#pragma unroll
  for (int i = 0; i < 4; i++) bits |= (sdf[ids[i]] > 0.0f) ? (1 << i) : 0;
  tetidx[t] = (uint8_t)bits;
  if (c_ntri[bits] == 0) return;
  int los[4];
  int c = 0;
#pragma unroll
  for (int e = 0; e < 6; e++) {
    int a = c_ea[e], b = c_eb[e];
    if ((((bits >> a) ^ (bits >> b)) & 1) == 0) continue;
    int va = ids[a], vb = ids[b];
    los[c++] = va < vb ? va : vb;
  }
  unsigned short st[4] = {0, 0, 0, 0};
  unsigned done = 0;
  unsigned short xtag = (unsigned short)(xcc << 13);
#pragma unroll
  for (int i = 0; i < 4; i++) {
    if (i >= c || (done & (1u << i))) continue;
    int cnt = 1;
#pragma unroll
    for (int j = 1; j < 4; j++)
      if (i + j < c && los[i + j] == los[i]) cnt++;
    int base = __hip_atomic_fetch_add(&myCnt[los[i]], cnt,
                                      __ATOMIC_RELAXED, __HIP_MEMORY_SCOPE_WORKGROUP);
    int k = 0;
#pragma unroll
    for (int j = 0; j < 4; j++) {
      if (i + j < c && los[i + j] == los[i]) {
        st[i + j] = (unsigned short)((base + k) | xtag);
        k++;
        done |= 1u << (i + j);
      }
    }
  }
  stash[t] = make_ushort4(st[0], st[1], st[2], st[3]);
}

// ---------------- per-bucket XCD prefix + total ---------------------------------
__global__ void k_xcdoff(int* __restrict__ xoff, int* __restrict__ bucketCnt, int nv) {
  int v = blockIdx.x * blockDim.x + threadIdx.x;
  if (v >= nv) return;
  int run = 0;
#pragma unroll
  for (int x = 0; x < NXCD; x++) {
    int c = xoff[(size_t)x * nv + v];
    xoff[(size_t)x * nv + v] = run;
    run += c;
  }
  bucketCnt[v] = run;
}

// ---------------- block exclusive scan helpers --------------------------------
__device__ inline unsigned long long blkExclU64(unsigned long long val, unsigned long long* sh) {
  int tid = threadIdx.x;
  sh[tid] = val; __syncthreads();
  for (int st = 1; st < SB; st <<= 1) {
    unsigned long long add = (tid >= st) ? sh[tid - st] : 0ull;
    __syncthreads();
    sh[tid] += add;
    __syncthreads();
  }
  return sh[tid] - val;
}
__device__ inline int blkExclI32(int val, int* sh) {
  int tid = threadIdx.x;
  sh[tid] = val; __syncthreads();
  for (int st = 1; st < SB; st <<= 1) {
    int add = (tid >= st) ? sh[tid - st] : 0;
    __syncthreads();
    sh[tid] += add;
    __syncthreads();
  }
  return sh[tid] - val;
}

// ---------------- pass1 (merged): tet block-totals + bucketCnt block-totals ---
__global__ void k_pass1(const uint8_t* __restrict__ tetidx, int nt,
                        const int* __restrict__ bucketCnt, int nv,
                        unsigned long long* __restrict__ btU, int* __restrict__ btI, int nb_t) {
  __shared__ unsigned long long shU[SB];
  int* shI = (int*)shU;
  if ((int)blockIdx.x < nb_t) {
    int base = blockIdx.x * SCHUNK + threadIdx.x * SI;
    unsigned long long s = 0;
    for (int k = 0; k < SI; k++) {
      int i = base + k;
      if (i < nt) {
        int n3 = c_ntri[tetidx[i]];
        s += (n3 == 1 ? 1ull : 0ull) + (n3 == 2 ? (1ull << 32) : 0ull);
      }
    }
    shU[threadIdx.x] = s; __syncthreads();
    for (int st = SB / 2; st > 0; st >>= 1) {
      if (threadIdx.x < st) shU[threadIdx.x] += shU[threadIdx.x + st];
      __syncthreads();
    }
    if (threadIdx.x == 0) btU[blockIdx.x] = shU[0];
  } else {
    int bid = blockIdx.x - nb_t;
    int base = bid * SCHUNK + threadIdx.x * SI;
    int s = 0;
    for (int k = 0; k < SI; k++) { int i = base + k; if (i < nv) s += bucketCnt[i]; }
    shI[threadIdx.x] = s; __syncthreads();
    for (int st = SB / 2; st > 0; st >>= 1) {
      if (threadIdx.x < st) shI[threadIdx.x] += shI[threadIdx.x + st];
      __syncthreads();
    }
    if (threadIdx.x == 0) btI[bid] = shI[0];
  }
}

// ---------------- middle scans (merged, 2 blocks) ------------------------------
__global__ void k_scanmid(unsigned long long* __restrict__ btU, int nbU,
                          int* __restrict__ btI, int nbI, int* __restrict__ scal) {
  __shared__ unsigned long long shU[SB];
  __shared__ unsigned long long carryU;
  int* shI = (int*)shU;
  __shared__ int carryI;
  if (blockIdx.x == 0) {
    if (threadIdx.x == 0) carryU = 0;
    __syncthreads();
    for (int base = 0; base < nbU; base += SB) {
      int i = base + threadIdx.x;
      unsigned long long v = (i < nbU) ? btU[i] : 0ull;
      unsigned long long ex = blkExclU64(v, shU);
      unsigned long long carry = carryU;
      if (i < nbU) btU[i] = carry + ex;
      __syncthreads();
      if (threadIdx.x == SB - 1) carryU = carry + ex + v;
      __syncthreads();
    }
    if (threadIdx.x == 0) {
      scal[0] = (int)(carryU & 0xffffffffull);
      scal[1] = (int)(carryU >> 32);
    }
  } else {
    if (threadIdx.x == 0) carryI = 0;
    __syncthreads();
    for (int base = 0; base < nbI; base += SB) {
      int i = base + threadIdx.x;
      int v = (i < nbI) ? btI[i] : 0;
      int ex = blkExclI32(v, shI);
      int carry = carryI;
      if (i < nbI) btI[i] = carry + ex;
      __syncthreads();
      if (threadIdx.x == SB - 1) carryI = carry + ex + v;
      __syncthreads();
    }
    if (threadIdx.x == 0) scal[2] = carryI;
  }
}

// ---------------- pass3: rowIdx (u32) + bucketOff + fold bucketOff into xoff ---
__global__ void k_pass3(const uint8_t* __restrict__ tetidx, int nt,
                        const int* __restrict__ bucketCnt, int nv,
                        const unsigned long long* __restrict__ btU, const int* __restrict__ btI,
                        const int* __restrict__ scal,
                        unsigned* __restrict__ rowIdx, int* __restrict__ bucketOff,
                        int* __restrict__ xoff, int nb_t) {
  __shared__ unsigned long long shU[SB];
  int* shI = (int*)shU;
  if ((int)blockIdx.x < nb_t) {
    int M1 = scal[0];
    int base = blockIdx.x * SCHUNK + threadIdx.x * SI;
    unsigned long long vals[SI];
    int n3s[SI];
    unsigned long long s = 0;
    for (int k = 0; k < SI; k++) {
      int i = base + k;
      unsigned long long v = 0;
      int n3 = 0;
      if (i < nt) {
        n3 = c_ntri[tetidx[i]];
        v = (n3 == 1 ? 1ull : 0ull) + (n3 == 2 ? (1ull << 32) : 0ull);
      }
      n3s[k] = n3;
      vals[k] = s; s += v;
    }
    unsigned long long thrOff = blkExclU64(s, shU);
    unsigned long long off = btU[blockIdx.x] + thrOff;
    for (int k = 0; k < SI; k++) {
      int i = base + k;
      if (i < nt) {
        unsigned long long r = off + vals[k];
        unsigned row = (n3s[k] == 1) ? (unsigned)(r & 0xffffffffull)
                                     : (unsigned)(M1 + 2 * (int)(r >> 32));
        rowIdx[i] = row;
      }
    }
  } else {
    int bid = blockIdx.x - nb_t;
    int base = bid * SCHUNK + threadIdx.x * SI;
    int vals[SI];
    int s = 0;
    for (int k = 0; k < SI; k++) {
      int i = base + k;
      int v = (i < nv) ? bucketCnt[i] : 0;
      vals[k] = s; s += v;
    }
    int thrOff = blkExclI32(s, shI);
    int off = btI[bid] + thrOff;
    for (int k = 0; k < SI; k++) {
      int i = base + k;
      if (i < nv) {
        int val = off + vals[k];
        bucketOff[i] = val;
#pragma unroll
        for (int x = 0; x < NXCD; x++) xoff[(size_t)x * nv + i] += val;
      }
    }
  }
}

// ---------------- generic i32 scan kernels (unique-count chain) ----------------
__global__ void k_i32scan1(const int* __restrict__ src, int* __restrict__ bt, int n) {
  __shared__ int sh[SB];
  int base = blockIdx.x * SCHUNK + threadIdx.x * SI;
  int s = 0;
  for (int k = 0; k < SI; k++) { int i = base + k; if (i < n) s += src[i]; }
  sh[threadIdx.x] = s; __syncthreads();
  for (int st = SB / 2; st > 0; st >>= 1) {
    if (threadIdx.x < st) sh[threadIdx.x] += sh[threadIdx.x + st];
    __syncthreads();
  }
  if (threadIdx.x == 0) bt[blockIdx.x] = sh[0];
}

// unique scanblk + fold offsets: scal[3]=E, then 4/5/6
__global__ void k_uscanblk(int* __restrict__ bt, int nb, int* __restrict__ scal, int uvsElems) {
  __shared__ int sh[SB];
  __shared__ int carrySh;
  if (threadIdx.x == 0) carrySh = 0;
  __syncthreads();
  for (int base = 0; base < nb; base += SB) {
    int i = base + threadIdx.x;
    int v = (i < nb) ? bt[i] : 0;
    int ex = blkExclI32(v, sh);
    int carry = carrySh;
    if (i < nb) bt[i] = carry + ex;
    __syncthreads();
    if (threadIdx.x == SB - 1) carrySh = carry + ex + v;
    __syncthreads();
  }
  if (threadIdx.x == 0) {
    int E = carrySh;
    scal[3] = E;
    int M1 = scal[0], M2 = scal[1];
    int F = M1 + 2 * M2;
    scal[4] = 3 * E;
    scal[5] = 3 * E + 3 * F;
    scal[6] = scal[5] + uvsElems;
  }
}

__global__ void k_i32scan3(const int* __restrict__ src, const int* __restrict__ bt,
                           int* __restrict__ dst, int n) {
  __shared__ int sh[SB];
  int base = blockIdx.x * SCHUNK + threadIdx.x * SI;
  int vals[SI];
  int s = 0;
  for (int k = 0; k < SI; k++) {
    int i = base + k;
    int v = (i < n) ? src[i] : 0;
    vals[k] = s; s += v;
  }
  int thrOff = blkExclI32(s, sh);
  int off = bt[blockIdx.x] + thrOff;
  for (int k = 0; k < SI; k++) {
    int i = base + k;
    if (i < n) dst[i] = off + vals[k];
  }
}

// ---------------- scatter: hi values + absolute occurrence index per tet -------
// abs = xoff[xcd][lo] + local_slot  (single gather; xoff already includes
// bucketOff + per-XCD prefix).
__global__ void k_scatter(const int4* __restrict__ tet, const uint8_t* __restrict__ tetidx,
                          const int* __restrict__ xoff, const ushort4* __restrict__ stash,
                          unsigned* __restrict__ edges32, int4* __restrict__ stashAbs,
                          int nt, int nv) {
  int t = blockIdx.x * blockDim.x + threadIdx.x;
  if (t >= nt) return;
  int bits = tetidx[t];
  if (c_ntri[bits] == 0) return;
  int4 v = tet[t];
  int ids[4] = {v.x, v.y, v.z, v.w};
  ushort4 stv = stash[t];
  unsigned short sta[4] = {stv.x, stv.y, stv.z, stv.w};
  int sa[4] = {0, 0, 0, 0};
  int c = 0;
#pragma unroll
  for (int e = 0; e < 6; e++) {
    int a = c_ea[e], b = c_eb[e];
    if ((((bits >> a) ^ (bits >> b)) & 1) == 0) continue;
    int va = ids[a], vb = ids[b];
    int lo = va < vb ? va : vb;
    int hi = va < vb ? vb : va;
    unsigned sv = sta[c];
    int xcd = (int)(sv >> 13);
    int slot = (int)(sv & SLOTMASK);
    int abs = xoff[(size_t)xcd * nv + lo] + slot;
    edges32[abs] = (unsigned)hi;
    sa[c] = abs;
    c++;
  }
  stashAbs[t] = make_int4(sa[0], sa[1], sa[2], sa[3]);
}

// ---------------- rank-by-counting, load-balanced partition --------------------
__global__ __launch_bounds__(SB) void k_rankuniq(
    const int* __restrict__ bucketOff, const unsigned* __restrict__ edges32,
    unsigned short* __restrict__ hrankArr, unsigned* __restrict__ edgesU,
    int* __restrict__ uniqueCnt, int* __restrict__ tmpHead,
    const int* __restrict__ scal, int nv) {
  __shared__ unsigned sh[LDSN];
  __shared__ unsigned shB[LDSN];
  __shared__ int shVS, shVE;
  int totSlots = scal[2];
  long long s0 = (long long)blockIdx.x * C2;
  long long s1 = s0 + C2;
  if (threadIdx.x == 0) {
    int lo = 0, hi = nv;
    while (lo < hi) { int mid = (lo + hi) >> 1;
      long long key = (long long)bucketOff[mid] + mid;
      if (key < s0) lo = mid + 1; else hi = mid; }
    shVS = lo;
    hi = nv;
    while (lo < hi) { int mid = (lo + hi) >> 1;
      long long key = (long long)bucketOff[mid] + mid;
      if (key < s1) lo = mid + 1; else hi = mid; }
    shVE = lo;
  }
  __syncthreads();
  int vS = shVS, vE = shVE;
  if (vS >= vE) return;
  int occS = bucketOff[vS];
  int occE = (vE < nv) ? bucketOff[vE] : totSlots;
  int cnt = occE - occS;
  if (cnt <= LDSN) {
    for (int v = vS + threadIdx.x; v < vE; v += SB) {
      int o = bucketOff[v];
      int nx = (v + 1 < nv) ? bucketOff[v + 1] : totSlots;
      if (nx > o) {
        unsigned pack = ((unsigned)(o - occS) << 16) | (unsigned)(nx - occS);
        for (int k = o; k < nx; k++) shB[k - occS] = pack;
      }
    }
    for (int i = threadIdx.x; i < cnt; i += SB) sh[i] = edges32[occS + i];
    __syncthreads();
    // P2: head flags
    for (int i = threadIdx.x; i < cnt; i += SB) {
      int lb = (int)(shB[i] >> 16);
      unsigned myv = sh[i] & VMASK;
      bool head = true;
      for (int k = lb; k < i; k++)
        if (((sh[k] ^ myv) & VMASK) == 0) { head = false; break; }
      if (head) sh[i] = myv | HEADBIT;
    }
    __syncthreads();
    // P3: ranks + compact heads
    for (int i = threadIdx.x; i < cnt; i += SB) {
      unsigned b = shB[i];
      int lb = (int)(b >> 16), le = (int)(b & 0xffffu);
      unsigned w0 = sh[i];
      unsigned myv = w0 & VMASK;
      int rank = 0;
      for (int k = lb; k < le; k++) {
        unsigned w = sh[k];
        rank += ((w & HEADBIT) != 0u && (w & VMASK) < myv) ? 1 : 0;
      }
      hrankArr[occS + i] = (unsigned short)rank;
      if (w0 & HEADBIT) edgesU[occS + lb + rank] = myv;
    }
    // P4: unique count per bucket
    for (int v = vS + threadIdx.x; v < vE; v += SB) {
      int o = bucketOff[v];
      int nx = (v + 1 < nv) ? bucketOff[v + 1] : totSlots;
      int u = 0;
      for (int k = o - occS; k < nx - occS; k++) u += (sh[k] & HEADBIT) ? 1 : 0;
      uniqueCnt[v] = u;
    }
  } else {
    // correctness fallback (adversarial data only): per-bucket O(n^2) in global
    for (int v = vS + threadIdx.x; v < vE; v += SB) {
      int o = bucketOff[v];
      int nx = (v + 1 < nv) ? bucketOff[v + 1] : totSlots;
      int n = nx - o;
      if (n <= 0) { uniqueCnt[v] = 0; continue; }
      for (int j = 0; j < n; j++) {
        unsigned myv = edges32[o + j];
        int head = 1;
        for (int k = 0; k < j; k++) if (edges32[o + k] == myv) { head = 0; break; }
        tmpHead[o + j] = head;
      }
      int u = 0;
      for (int j = 0; j < n; j++) {
        unsigned myv = edges32[o + j];
        int rank = 0;
        for (int k = 0; k < n; k++)
          rank += (tmpHead[o + k] && edges32[o + k] < myv) ? 1 : 0;
        hrankArr[o + j] = (unsigned short)rank;
        if (tmpHead[o + j]) { edgesU[o + rank] = myv; u++; }
      }
      uniqueCnt[v] = u;
    }
  }
}

// ---------------- verts + grank conversion (bucket-sequential, cheap) ----------
__global__ __launch_bounds__(SB) void k_verts(
    const int* __restrict__ bucketOff, const int* __restrict__ uniqueOff,
    const unsigned short* __restrict__ hrankArr, const unsigned* __restrict__ edgesU,
    unsigned* __restrict__ grank, const float* __restrict__ pos, const float* __restrict__ sdf,
    const int* __restrict__ scal, float* __restrict__ out, int nv) {
  __shared__ int shUO[SB + 1];
  __shared__ int shBO[SB + 1];
  int v0 = blockIdx.x * SB;
  int totSlots = scal[2];
  int E = scal[3];
  for (int j = threadIdx.x; j <= SB; j += SB) {
    int gv = v0 + j;
    shUO[j] = (gv < nv) ? uniqueOff[gv] : E;
    shBO[j] = (gv < nv) ? bucketOff[gv] : totSlots;
  }
  __syncthreads();
  int v = v0 + threadIdx.x;
  if (v < nv) {
    int boff = shBO[threadIdx.x];
    int bend = shBO[threadIdx.x + 1];
    int uoff = shUO[threadIdx.x];
    for (int k = boff; k < bend; k++) grank[k] = (unsigned)(uoff + (int)hrankArr[k]);
  }
  int Ustart = shUO[0];
  int Utot = shUO[SB] - Ustart;
  for (int i = threadIdx.x; i < Utot; i += SB) {
    int gi = Ustart + i;
    int lo = 0, hi = SB;
    while (hi - lo > 1) { int mid = (lo + hi) >> 1; if (shUO[mid] <= gi) lo = mid; else hi = mid; }
    int rhat = gi - shUO[lo];
    int hiV = (int)edgesU[shBO[lo] + rhat];
    int loV = v0 + lo;
    float s0 = sdf[loV];
    float ns1 = -sdf[hiV];
    float denom = s0 + ns1;            // matches reference s.sum(1)
    float w0 = ns1 / denom;
    float w1 = s0 / denom;
    out[3 * gi + 0] = pos[3 * loV + 0] * w0 + pos[3 * hiV + 0] * w1;
    out[3 * gi + 1] = pos[3 * loV + 1] * w0 + pos[3 * hiV + 1] * w1;
    out[3 * gi + 2] = pos[3 * loV + 2] * w0 + pos[3 * hiV + 2] * w1;
  }
}

// ---------------- faces + uv_idx (stream stashAbs; ONE random gather: grank) ---
__global__ void k_face(const uint8_t* __restrict__ tetidx, const unsigned* __restrict__ rowIdx,
                       const int* __restrict__ scal, const int4* __restrict__ stashAbs,
                       const unsigned* __restrict__ grank, float* __restrict__ out, int nt) {
  int t = blockIdx.x * blockDim.x + threadIdx.x;
  if (t >= nt) return;
  int bits = tetidx[t];
  int nt3 = c_ntri[bits];
  if (nt3 == 0) return;
  int4 sabs = stashAbs[t];
  int sa[4] = {sabs.x, sabs.y, sabs.z, sabs.w};
  int rk[6];
  int c = 0;
#pragma unroll
  for (int e = 0; e < 6; e++) {
    int a = c_ea[e], b = c_eb[e];
    if ((((bits >> a) ^ (bits >> b)) & 1) == 0) continue;
    rk[e] = (int)grank[sa[c++]];
  }
  int row = (int)rowIdx[t];
  int facesOff = scal[4], uvidxOff = scal[6];
  float* f = out + facesOff + (size_t)3 * row;
  int npos = 3 * nt3;
  for (int p = 0; p < npos; p++) f[p] = (float)rk[c_tri[bits][p]];
  float* o = out + uvidxOff + (size_t)3 * row;
  float bt4 = (float)(4 * t);
  o[0] = bt4; o[1] = bt4 + 1.0f; o[2] = bt4 + 2.0f;
  if (nt3 == 2) { o[3] = bt4; o[4] = bt4 + 2.0f; o[5] = bt4 + 3.0f; }
}

// ---------------- uvs (float4 stores) -------------------------------------------
__global__ void k_uvs(const int* __restrict__ scal, float* __restrict__ out, int N) {
  int i = blockIdx.x * blockDim.x + threadIdx.x;
  int total = N * N;
  if (i >= total) return;
  int ty = i / N, tx = i - ty * N;
  float x = (float)tx / (float)N;
  float y = (float)ty / (float)N;
  float pad = (float)(0.9 / (double)N);
  float* o = out + scal[5] + (size_t)i * 8;
  float4 a = make_float4(x, y, x + pad, y);
  float4 b = make_float4(x + pad, y + pad, x, y + pad);
  *(float4*)(o) = a;
  *(float4*)(o + 4) = b;
}

extern "C" void kernel_launch(void* const* d_in, const int* in_sizes, int n_in,
                              void* d_out, int out_size, void* d_ws, size_t ws_size,
                              hipStream_t stream) {
  const float* pos = (const float*)d_in[0];
  const float* sdf = (const float*)d_in[1];
  const int* tet = (const int*)d_in[2];
  int nv = in_sizes[1];
  int nt = in_sizes[2] / 4;

  char* w = (char*)d_ws;
  size_t off = 0;
  auto A = [&](size_t bytes) -> char* {
    off = (off + 255) & ~(size_t)255;
    char* p = w + off;
    off += bytes;
    return p;
  };
  int* scal = (int*)A(64 * sizeof(int));
  uint8_t* tetidx = (uint8_t*)A((size_t)nt);
  unsigned* rowIdx = (unsigned*)A((size_t)nt * 4);
  int* xoff = (int*)A((size_t)NXCD * nv * 4);
  int* bucketCnt = (int*)A((size_t)nv * 4);
  int* bucketOff = (int*)A((size_t)nv * 4);
  int* uniqueCnt = (int*)A((size_t)nv * 4);
  int* uniqueOff = (int*)A((size_t)nv * 4);
  ushort4* stash = (ushort4*)A((size_t)nt * 8);
  int4* stashAbs = (int4*)A((size_t)nt * 16);
  unsigned short* hrankArr = (unsigned short*)A((size_t)nt * 4 * 2);
  unsigned* grank = (unsigned*)A((size_t)nt * 4 * 4);
  unsigned* edges32 = (unsigned*)A((size_t)nt * 4 * 4);
  unsigned* edgesU = (unsigned*)A((size_t)nt * 4 * 4);
  int* tmpHead = (int*)A((size_t)nt * 4 * 4);       // fallback scratch only
  unsigned long long* blockTotU = (unsigned long long*)A(8 * 4096);
  int* blockTotI = (int*)A(4 * 4096);

  hipMemsetAsync(xoff, 0, (size_t)NXCD * nv * 4, stream);

  int nb_t = (nt + SCHUNK - 1) / SCHUNK;
  int nb_v = (nv + SCHUNK - 1) / SCHUNK;
  int nbv_verts = (nv + SB - 1) / SB;
  long long maxKey = (long long)nt * 4 + nv;
  int nb_rank = (int)((maxKey + C2 - 1) / C2) + 1;

  k_classify<<<(nt + 255) / 256, 256, 0, stream>>>((const int4*)tet, sdf, tetidx, xoff,
                                                   stash, nt, nv);
  k_xcdoff<<<(nv + 255) / 256, 256, 0, stream>>>(xoff, bucketCnt, nv);

  k_pass1<<<nb_t + nb_v, SB, 0, stream>>>(tetidx, nt, bucketCnt, nv, blockTotU, blockTotI, nb_t);
  k_scanmid<<<2, SB, 0, stream>>>(blockTotU, nb_t, blockTotI, nb_v, scal);
  k_pass3<<<nb_t + nb_v, SB, 0, stream>>>(tetidx, nt, bucketCnt, nv, blockTotU, blockTotI,
                                          scal, rowIdx, bucketOff, xoff, nb_t);

  k_scatter<<<(nt + 255) / 256, 256, 0, stream>>>((const int4*)tet, tetidx, xoff,
                                                  stash, edges32, stashAbs, nt, nv);

  k_rankuniq<<<nb_rank, SB, 0, stream>>>(bucketOff, edges32, hrankArr, edgesU,
                                         uniqueCnt, tmpHead, scal, nv);

  long long maxidx = (long long)nt * 2;
  int N = (int)ceil(sqrt((double)((maxidx + 1) / 2)));
  int uvsElems = N * N * 8;

  k_i32scan1<<<nb_v, SB, 0, stream>>>(uniqueCnt, blockTotI, nv);
  k_uscanblk<<<1, SB, 0, stream>>>(blockTotI, nb_v, scal, uvsElems);
  k_i32scan3<<<nb_v, SB, 0, stream>>>(uniqueCnt, blockTotI, uniqueOff, nv);

  k_verts<<<nbv_verts, SB, 0, stream>>>(bucketOff, uniqueOff, hrankArr, edgesU, grank,
                                        pos, sdf, scal, (float*)d_out, nv);
  k_face<<<(nt + 255) / 256, 256, 0, stream>>>(tetidx, rowIdx, scal, stashAbs, grank,
                                               (float*)d_out, nt);
  k_uvs<<<(N * N + 255) / 256, 256, 0, stream>>>(scal, (float*)d_out, N);
}

// Round 15
// 626.789 us; speedup vs baseline: 1.1007x; 1.1007x over previous
//
#include <hip/hip_runtime.h>
#include <stdint.h>
#include <math.h>

#define SB 256
#define SI 8
#define SCHUNK (SB*SI)
#define C2 2048            // occurrence-key chunk per block
#define LDSN (C2 + 256)    // + margin for the boundary bucket (max bucket ~74)
#define HEADBIT 0x40000000u
#define VMASK   0x3FFFFFFFu

__constant__ int c_tri[16][6] = {
  {-1,-1,-1,-1,-1,-1},{1,0,2,-1,-1,-1},{4,0,3,-1,-1,-1},{1,4,2,1,3,4},
  {3,1,5,-1,-1,-1},{2,3,0,2,5,3},{1,4,0,1,5,4},{4,2,5,-1,-1,-1},
  {4,5,2,-1,-1,-1},{4,1,0,4,5,1},{3,2,0,3,5,2},{1,3,5,-1,-1,-1},
  {4,1,2,4,3,1},{3,0,4,-1,-1,-1},{2,0,1,-1,-1,-1},{-1,-1,-1,-1,-1,-1}};
__constant__ int c_ntri[16] = {0,1,1,2,1,2,2,1,1,2,2,1,2,1,1,0};
__constant__ int c_ea[6] = {0,0,0,1,1,2};
__constant__ int c_eb[6] = {1,2,3,2,3,3};

// ---------------- classify tets: occupancy bits + bucket count + slot stash --
// One atomicAdd per DISTINCT lo within the tet. Memory-side atomic RMW count
// is the cost driver (r11: WRITE_SIZE ∝ count; r10 NT-hints and r14 XCD-local
// scope both refuted as levers).
__global__ void k_classify(const int4* __restrict__ tet, const float* __restrict__ sdf,
                           uint8_t* __restrict__ tetidx, int* __restrict__ bucketCnt,
                           ushort4* __restrict__ stash, int nt) {
  int t = blockIdx.x * blockDim.x + threadIdx.x;
  if (t >= nt) return;
  int4 v = tet[t];
  int ids[4] = {v.x, v.y, v.z, v.w};
  int bits = 0;
#pragma unroll
  for (int i = 0; i < 4; i++) bits |= (sdf[ids[i]] > 0.0f) ? (1 << i) : 0;
  tetidx[t] = (uint8_t)bits;
  if (c_ntri[bits] == 0) return;
  int los[4];
  int c = 0;
#pragma unroll
  for (int e = 0; e < 6; e++) {
    int a = c_ea[e], b = c_eb[e];
    if ((((bits >> a) ^ (bits >> b)) & 1) == 0) continue;
    int va = ids[a], vb = ids[b];
    los[c++] = va < vb ? va : vb;
  }
  unsigned short st[4] = {0, 0, 0, 0};
  unsigned done = 0;
#pragma unroll
  for (int i = 0; i < 4; i++) {
    if (i >= c || (done & (1u << i))) continue;
    int cnt = 1;
#pragma unroll
    for (int j = 1; j < 4; j++)
      if (i + j < c && los[i + j] == los[i]) cnt++;
    int base = atomicAdd(&bucketCnt[los[i]], cnt);
    int k = 0;
#pragma unroll
    for (int j = 0; j < 4; j++) {
      if (i + j < c && los[i + j] == los[i]) {
        st[i + j] = (unsigned short)(base + k);
        k++;
        done |= 1u << (i + j);
      }
    }
  }
  stash[t] = make_ushort4(st[0], st[1], st[2], st[3]);
}

// ---------------- block exclusive scan helpers --------------------------------
__device__ inline unsigned long long blkExclU64(unsigned long long val, unsigned long long* sh) {
  int tid = threadIdx.x;
  sh[tid] = val; __syncthreads();
  for (int st = 1; st < SB; st <<= 1) {
    unsigned long long add = (tid >= st) ? sh[tid - st] : 0ull;
    __syncthreads();
    sh[tid] += add;
    __syncthreads();
  }
  return sh[tid] - val;
}
__device__ inline int blkExclI32(int val, int* sh) {
  int tid = threadIdx.x;
  sh[tid] = val; __syncthreads();
  for (int st = 1; st < SB; st <<= 1) {
    int add = (tid >= st) ? sh[tid - st] : 0;
    __syncthreads();
    sh[tid] += add;
    __syncthreads();
  }
  return sh[tid] - val;
}

// ---------------- pass1 (merged): tet block-totals + bucketCnt block-totals ---
__global__ void k_pass1(const uint8_t* __restrict__ tetidx, int nt,
                        const int* __restrict__ bucketCnt, int nv,
                        unsigned long long* __restrict__ btU, int* __restrict__ btI, int nb_t) {
  __shared__ unsigned long long shU[SB];
  int* shI = (int*)shU;
  if ((int)blockIdx.x < nb_t) {
    int base = blockIdx.x * SCHUNK + threadIdx.x * SI;
    unsigned long long s = 0;
    for (int k = 0; k < SI; k++) {
      int i = base + k;
      if (i < nt) {
        int n3 = c_ntri[tetidx[i]];
        s += (n3 == 1 ? 1ull : 0ull) + (n3 == 2 ? (1ull << 32) : 0ull);
      }
    }
    shU[threadIdx.x] = s; __syncthreads();
    for (int st = SB / 2; st > 0; st >>= 1) {
      if (threadIdx.x < st) shU[threadIdx.x] += shU[threadIdx.x + st];
      __syncthreads();
    }
    if (threadIdx.x == 0) btU[blockIdx.x] = shU[0];
  } else {
    int bid = blockIdx.x - nb_t;
    int base = bid * SCHUNK + threadIdx.x * SI;
    int s = 0;
    for (int k = 0; k < SI; k++) { int i = base + k; if (i < nv) s += bucketCnt[i]; }
    shI[threadIdx.x] = s; __syncthreads();
    for (int st = SB / 2; st > 0; st >>= 1) {
      if (threadIdx.x < st) shI[threadIdx.x] += shI[threadIdx.x + st];
      __syncthreads();
    }
    if (threadIdx.x == 0) btI[bid] = shI[0];
  }
}

// ---------------- middle scans (merged, 2 blocks) ------------------------------
__global__ void k_scanmid(unsigned long long* __restrict__ btU, int nbU,
                          int* __restrict__ btI, int nbI, int* __restrict__ scal) {
  __shared__ unsigned long long shU[SB];
  __shared__ unsigned long long carryU;
  int* shI = (int*)shU;
  __shared__ int carryI;
  if (blockIdx.x == 0) {
    if (threadIdx.x == 0) carryU = 0;
    __syncthreads();
    for (int base = 0; base < nbU; base += SB) {
      int i = base + threadIdx.x;
      unsigned long long v = (i < nbU) ? btU[i] : 0ull;
      unsigned long long ex = blkExclU64(v, shU);
      unsigned long long carry = carryU;
      if (i < nbU) btU[i] = carry + ex;
      __syncthreads();
      if (threadIdx.x == SB - 1) carryU = carry + ex + v;
      __syncthreads();
    }
    if (threadIdx.x == 0) {
      scal[0] = (int)(carryU & 0xffffffffull);
      scal[1] = (int)(carryU >> 32);
    }
  } else {
    if (threadIdx.x == 0) carryI = 0;
    __syncthreads();
    for (int base = 0; base < nbI; base += SB) {
      int i = base + threadIdx.x;
      int v = (i < nbI) ? btI[i] : 0;
      int ex = blkExclI32(v, shI);
      int carry = carryI;
      if (i < nbI) btI[i] = carry + ex;
      __syncthreads();
      if (threadIdx.x == SB - 1) carryI = carry + ex + v;
      __syncthreads();
    }
    if (threadIdx.x == 0) scal[2] = carryI;
  }
}

// ---------------- pass3 (merged): rowIdx (u32, final face row) + bucketOff -----
__global__ void k_pass3(const uint8_t* __restrict__ tetidx, int nt,
                        const int* __restrict__ bucketCnt, int nv,
                        const unsigned long long* __restrict__ btU, const int* __restrict__ btI,
                        const int* __restrict__ scal,
                        unsigned* __restrict__ rowIdx, int* __restrict__ bucketOff,
                        int nb_t) {
  __shared__ unsigned long long shU[SB];
  int* shI = (int*)shU;
  if ((int)blockIdx.x < nb_t) {
    int M1 = scal[0];
    int base = blockIdx.x * SCHUNK + threadIdx.x * SI;
    unsigned long long vals[SI];
    int n3s[SI];
    unsigned long long s = 0;
    for (int k = 0; k < SI; k++) {
      int i = base + k;
      unsigned long long v = 0;
      int n3 = 0;
      if (i < nt) {
        n3 = c_ntri[tetidx[i]];
        v = (n3 == 1 ? 1ull : 0ull) + (n3 == 2 ? (1ull << 32) : 0ull);
      }
      n3s[k] = n3;
      vals[k] = s; s += v;
    }
    unsigned long long thrOff = blkExclU64(s, shU);
    unsigned long long off = btU[blockIdx.x] + thrOff;
    for (int k = 0; k < SI; k++) {
      int i = base + k;
      if (i < nt) {
        unsigned long long r = off + vals[k];
        unsigned row = (n3s[k] == 1) ? (unsigned)(r & 0xffffffffull)
                                     : (unsigned)(M1 + 2 * (int)(r >> 32));
        rowIdx[i] = row;
      }
    }
  } else {
    int bid = blockIdx.x - nb_t;
    int base = bid * SCHUNK + threadIdx.x * SI;
    int vals[SI];
    int s = 0;
    for (int k = 0; k < SI; k++) {
      int i = base + k;
      int v = (i < nv) ? bucketCnt[i] : 0;
      vals[k] = s; s += v;
    }
    int thrOff = blkExclI32(s, shI);
    int off = btI[bid] + thrOff;
    for (int k = 0; k < SI; k++) {
      int i = base + k;
      if (i < nv) bucketOff[i] = off + vals[k];
    }
  }
}

// ---------------- generic i32 scan kernels (unique-count chain) ----------------
__global__ void k_i32scan1(const int* __restrict__ src, int* __restrict__ bt, int n) {
  __shared__ int sh[SB];
  int base = blockIdx.x * SCHUNK + threadIdx.x * SI;
  int s = 0;
  for (int k = 0; k < SI; k++) { int i = base + k; if (i < n) s += src[i]; }
  sh[threadIdx.x] = s; __syncthreads();
  for (int st = SB / 2; st > 0; st >>= 1) {
    if (threadIdx.x < st) sh[threadIdx.x] += sh[threadIdx.x + st];
    __syncthreads();
  }
  if (threadIdx.x == 0) bt[blockIdx.x] = sh[0];
}

// unique scanblk + fold offsets: scal[3]=E, then 4/5/6
__global__ void k_uscanblk(int* __restrict__ bt, int nb, int* __restrict__ scal, int uvsElems) {
  __shared__ int sh[SB];
  __shared__ int carrySh;
  if (threadIdx.x == 0) carrySh = 0;
  __syncthreads();
  for (int base = 0; base < nb; base += SB) {
    int i = base + threadIdx.x;
    int v = (i < nb) ? bt[i] : 0;
    int ex = blkExclI32(v, sh);
    int carry = carrySh;
    if (i < nb) bt[i] = carry + ex;
    __syncthreads();
    if (threadIdx.x == SB - 1) carrySh = carry + ex + v;
    __syncthreads();
  }
  if (threadIdx.x == 0) {
    int E = carrySh;
    scal[3] = E;
    int M1 = scal[0], M2 = scal[1];
    int F = M1 + 2 * M2;
    scal[4] = 3 * E;
    scal[5] = 3 * E + 3 * F;
    scal[6] = scal[5] + uvsElems;
  }
}

__global__ void k_i32scan3(const int* __restrict__ src, const int* __restrict__ bt,
                           int* __restrict__ dst, int n) {
  __shared__ int sh[SB];
  int base = blockIdx.x * SCHUNK + threadIdx.x * SI;
  int vals[SI];
  int s = 0;
  for (int k = 0; k < SI; k++) {
    int i = base + k;
    int v = (i < n) ? src[i] : 0;
    vals[k] = s; s += v;
  }
  int thrOff = blkExclI32(s, sh);
  int off = bt[blockIdx.x] + thrOff;
  for (int k = 0; k < SI; k++) {
    int i = base + k;
    if (i < n) dst[i] = off + vals[k];
  }
}

// ---------------- scatter: hi values + absolute occurrence index per tet -------
__global__ void k_scatter(const int4* __restrict__ tet, const uint8_t* __restrict__ tetidx,
                          const int* __restrict__ bucketOff, const ushort4* __restrict__ stash,
                          unsigned* __restrict__ edges32, int4* __restrict__ stashAbs, int nt) {
  int t = blockIdx.x * blockDim.x + threadIdx.x;
  if (t >= nt) return;
  int bits = tetidx[t];
  if (c_ntri[bits] == 0) return;
  int4 v = tet[t];
  int ids[4] = {v.x, v.y, v.z, v.w};
  ushort4 stv = stash[t];
  unsigned short sta[4] = {stv.x, stv.y, stv.z, stv.w};
  int sa[4] = {0, 0, 0, 0};
  int c = 0;
#pragma unroll
  for (int e = 0; e < 6; e++) {
    int a = c_ea[e], b = c_eb[e];
    if ((((bits >> a) ^ (bits >> b)) & 1) == 0) continue;
    int va = ids[a], vb = ids[b];
    int lo = va < vb ? va : vb;
    int hi = va < vb ? vb : va;
    int abs = bucketOff[lo] + (int)sta[c];
    edges32[abs] = (unsigned)hi;
    sa[c] = abs;
    c++;
  }
  stashAbs[t] = make_int4(sa[0], sa[1], sa[2], sa[3]);
}

// ---------------- rank-by-counting, load-balanced partition --------------------
// Block b owns buckets v with key(v)=bucketOff[v]+v in [b*C2,(b+1)*C2).
__global__ __launch_bounds__(SB) void k_rankuniq(
    const int* __restrict__ bucketOff, const unsigned* __restrict__ edges32,
    unsigned short* __restrict__ hrankArr, unsigned* __restrict__ edgesU,
    int* __restrict__ uniqueCnt, int* __restrict__ tmpHead,
    const int* __restrict__ scal, int nv) {
  __shared__ unsigned sh[LDSN];
  __shared__ unsigned shB[LDSN];
  __shared__ int shVS, shVE;
  int totSlots = scal[2];
  long long s0 = (long long)blockIdx.x * C2;
  long long s1 = s0 + C2;
  if (threadIdx.x == 0) {
    int lo = 0, hi = nv;
    while (lo < hi) { int mid = (lo + hi) >> 1;
      long long key = (long long)bucketOff[mid] + mid;
      if (key < s0) lo = mid + 1; else hi = mid; }
    shVS = lo;
    hi = nv;
    while (lo < hi) { int mid = (lo + hi) >> 1;
      long long key = (long long)bucketOff[mid] + mid;
      if (key < s1) lo = mid + 1; else hi = mid; }
    shVE = lo;
  }
  __syncthreads();
  int vS = shVS, vE = shVE;
  if (vS >= vE) return;
  int occS = bucketOff[vS];
  int occE = (vE < nv) ? bucketOff[vE] : totSlots;
  int cnt = occE - occS;
  if (cnt <= LDSN) {
    for (int v = vS + threadIdx.x; v < vE; v += SB) {
      int o = bucketOff[v];
      int nx = (v + 1 < nv) ? bucketOff[v + 1] : totSlots;
      if (nx > o) {
        unsigned pack = ((unsigned)(o - occS) << 16) | (unsigned)(nx - occS);
        for (int k = o; k < nx; k++) shB[k - occS] = pack;
      }
    }
    for (int i = threadIdx.x; i < cnt; i += SB) sh[i] = edges32[occS + i];
    __syncthreads();
    // P2: head flags
    for (int i = threadIdx.x; i < cnt; i += SB) {
      int lb = (int)(shB[i] >> 16);
      unsigned myv = sh[i] & VMASK;
      bool head = true;
      for (int k = lb; k < i; k++)
        if (((sh[k] ^ myv) & VMASK) == 0) { head = false; break; }
      if (head) sh[i] = myv | HEADBIT;
    }
    __syncthreads();
    // P3: ranks + compact heads
    for (int i = threadIdx.x; i < cnt; i += SB) {
      unsigned b = shB[i];
      int lb = (int)(b >> 16), le = (int)(b & 0xffffu);
      unsigned w0 = sh[i];
      unsigned myv = w0 & VMASK;
      int rank = 0;
      for (int k = lb; k < le; k++) {
        unsigned w = sh[k];
        rank += ((w & HEADBIT) != 0u && (w & VMASK) < myv) ? 1 : 0;
      }
      hrankArr[occS + i] = (unsigned short)rank;
      if (w0 & HEADBIT) edgesU[occS + lb + rank] = myv;
    }
    // P4: unique count per bucket
    for (int v = vS + threadIdx.x; v < vE; v += SB) {
      int o = bucketOff[v];
      int nx = (v + 1 < nv) ? bucketOff[v + 1] : totSlots;
      int u = 0;
      for (int k = o - occS; k < nx - occS; k++) u += (sh[k] & HEADBIT) ? 1 : 0;
      uniqueCnt[v] = u;
    }
  } else {
    // correctness fallback (adversarial data only): per-bucket O(n^2) in global
    for (int v = vS + threadIdx.x; v < vE; v += SB) {
      int o = bucketOff[v];
      int nx = (v + 1 < nv) ? bucketOff[v + 1] : totSlots;
      int n = nx - o;
      if (n <= 0) { uniqueCnt[v] = 0; continue; }
      for (int j = 0; j < n; j++) {
        unsigned myv = edges32[o + j];
        int head = 1;
        for (int k = 0; k < j; k++) if (edges32[o + k] == myv) { head = 0; break; }
        tmpHead[o + j] = head;
      }
      int u = 0;
      for (int j = 0; j < n; j++) {
        unsigned myv = edges32[o + j];
        int rank = 0;
        for (int k = 0; k < n; k++)
          rank += (tmpHead[o + k] && edges32[o + k] < myv) ? 1 : 0;
        hrankArr[o + j] = (unsigned short)rank;
        if (tmpHead[o + j]) { edgesU[o + rank] = myv; u++; }
      }
      uniqueCnt[v] = u;
    }
  }
}

// ---------------- verts + grank conversion (occurrence-parallel, coalesced) ----
__global__ __launch_bounds__(SB) void k_verts(
    const int* __restrict__ bucketOff, const int* __restrict__ uniqueOff,
    const unsigned short* __restrict__ hrankArr, const unsigned* __restrict__ edgesU,
    unsigned* __restrict__ grank, const float* __restrict__ pos, const float* __restrict__ sdf,
    const int* __restrict__ scal, float* __restrict__ out, int nv) {
  __shared__ int shUO[SB + 1];
  __shared__ int shBO[SB + 1];
  int v0 = blockIdx.x * SB;
  int totSlots = scal[2];
  int E = scal[3];
  for (int j = threadIdx.x; j <= SB; j += SB) {
    int gv = v0 + j;
    shUO[j] = (gv < nv) ? uniqueOff[gv] : E;
    shBO[j] = (gv < nv) ? bucketOff[gv] : totSlots;
  }
  __syncthreads();
  // grank: occurrence-parallel, coalesced read (hrankArr) and write (grank);
  // owning bucket located by 8-step bsearch in LDS.
  int occS = shBO[0];
  int occTot = shBO[SB] - occS;
  for (int k = threadIdx.x; k < occTot; k += SB) {
    int gk = occS + k;
    int lo = 0, hi = SB;
    while (hi - lo > 1) { int mid = (lo + hi) >> 1; if (shBO[mid] <= gk) lo = mid; else hi = mid; }
    grank[gk] = (unsigned)(shUO[lo] + (int)hrankArr[gk]);
  }
  int Ustart = shUO[0];
  int Utot = shUO[SB] - Ustart;
  for (int i = threadIdx.x; i < Utot; i += SB) {
    int gi = Ustart + i;
    int lo = 0, hi = SB;
    while (hi - lo > 1) { int mid = (lo + hi) >> 1; if (shUO[mid] <= gi) lo = mid; else hi = mid; }
    int rhat = gi - shUO[lo];
    int hiV = (int)edgesU[shBO[lo] + rhat];
    int loV = v0 + lo;
    float s0 = sdf[loV];
    float ns1 = -sdf[hiV];
    float denom = s0 + ns1;            // matches reference s.sum(1)
    float w0 = ns1 / denom;
    float w1 = s0 / denom;
    out[3 * gi + 0] = pos[3 * loV + 0] * w0 + pos[3 * hiV + 0] * w1;
    out[3 * gi + 1] = pos[3 * loV + 1] * w0 + pos[3 * hiV + 1] * w1;
    out[3 * gi + 2] = pos[3 * loV + 2] * w0 + pos[3 * hiV + 2] * w1;
  }
}

// ---------------- faces + uv_idx + uvs (fused; block-uniform branch) -----------
__global__ void k_face(const uint8_t* __restrict__ tetidx, const unsigned* __restrict__ rowIdx,
                       const int* __restrict__ scal, const int4* __restrict__ stashAbs,
                       const unsigned* __restrict__ grank, float* __restrict__ out,
                       int nt, int faceBlocks, int N) {
  if ((int)blockIdx.x >= faceBlocks) {
    // ---- uvs part ----
    int i = (blockIdx.x - faceBlocks) * blockDim.x + threadIdx.x;
    int total = N * N;
    if (i >= total) return;
    int ty = i / N, tx = i - ty * N;
    float x = (float)tx / (float)N;
    float y = (float)ty / (float)N;
    float pad = (float)(0.9 / (double)N);
    float* o = out + scal[5] + (size_t)i * 8;
    float4 a = make_float4(x, y, x + pad, y);
    float4 b = make_float4(x + pad, y + pad, x, y + pad);
    *(float4*)(o) = a;
    *(float4*)(o + 4) = b;
    return;
  }
  int t = blockIdx.x * blockDim.x + threadIdx.x;
  if (t >= nt) return;
  int bits = tetidx[t];
  int nt3 = c_ntri[bits];
  if (nt3 == 0) return;
  int4 sabs = stashAbs[t];
  int sa[4] = {sabs.x, sabs.y, sabs.z, sabs.w};
  int rk[6];
  int c = 0;
#pragma unroll
  for (int e = 0; e < 6; e++) {
    int a = c_ea[e], b = c_eb[e];
    if ((((bits >> a) ^ (bits >> b)) & 1) == 0) continue;
    rk[e] = (int)grank[sa[c++]];
  }
  int row = (int)rowIdx[t];
  int facesOff = scal[4], uvidxOff = scal[6];
  float* f = out + facesOff + (size_t)3 * row;
  int npos = 3 * nt3;
  for (int p = 0; p < npos; p++) f[p] = (float)rk[c_tri[bits][p]];
  float* o = out + uvidxOff + (size_t)3 * row;
  float bt4 = (float)(4 * t);
  o[0] = bt4; o[1] = bt4 + 1.0f; o[2] = bt4 + 2.0f;
  if (nt3 == 2) { o[3] = bt4; o[4] = bt4 + 2.0f; o[5] = bt4 + 3.0f; }
}

extern "C" void kernel_launch(void* const* d_in, const int* in_sizes, int n_in,
                              void* d_out, int out_size, void* d_ws, size_t ws_size,
                              hipStream_t stream) {
  const float* pos = (const float*)d_in[0];
  const float* sdf = (const float*)d_in[1];
  const int* tet = (const int*)d_in[2];
  int nv = in_sizes[1];
  int nt = in_sizes[2] / 4;

  char* w = (char*)d_ws;
  size_t off = 0;
  auto A = [&](size_t bytes) -> char* {
    off = (off + 255) & ~(size_t)255;
    char* p = w + off;
    off += bytes;
    return p;
  };
  int* scal = (int*)A(64 * sizeof(int));
  uint8_t* tetidx = (uint8_t*)A((size_t)nt);
  unsigned* rowIdx = (unsigned*)A((size_t)nt * 4);
  int* bucketCnt = (int*)A((size_t)nv * 4);
  int* bucketOff = (int*)A((size_t)nv * 4);
  int* uniqueCnt = (int*)A((size_t)nv * 4);
  int* uniqueOff = (int*)A((size_t)nv * 4);
  ushort4* stash = (ushort4*)A((size_t)nt * 8);
  int4* stashAbs = (int4*)A((size_t)nt * 16);
  unsigned short* hrankArr = (unsigned short*)A((size_t)nt * 4 * 2);
  unsigned* grank = (unsigned*)A((size_t)nt * 4 * 4);
  unsigned* edges32 = (unsigned*)A((size_t)nt * 4 * 4);
  unsigned* edgesU = (unsigned*)A((size_t)nt * 4 * 4);
  int* tmpHead = (int*)A((size_t)nt * 4 * 4);       // fallback scratch only
  unsigned long long* blockTotU = (unsigned long long*)A(8 * 4096);
  int* blockTotI = (int*)A(4 * 4096);

  hipMemsetAsync(bucketCnt, 0, (size_t)nv * 4, stream);

  int nb_t = (nt + SCHUNK - 1) / SCHUNK;
  int nb_v = (nv + SCHUNK - 1) / SCHUNK;
  int nbv_verts = (nv + SB - 1) / SB;
  long long maxKey = (long long)nt * 4 + nv;
  int nb_rank = (int)((maxKey + C2 - 1) / C2) + 1;

  k_classify<<<(nt + 255) / 256, 256, 0, stream>>>((const int4*)tet, sdf, tetidx, bucketCnt,
                                                   stash, nt);

  k_pass1<<<nb_t + nb_v, SB, 0, stream>>>(tetidx, nt, bucketCnt, nv, blockTotU, blockTotI, nb_t);
  k_scanmid<<<2, SB, 0, stream>>>(blockTotU, nb_t, blockTotI, nb_v, scal);
  k_pass3<<<nb_t + nb_v, SB, 0, stream>>>(tetidx, nt, bucketCnt, nv, blockTotU, blockTotI,
                                          scal, rowIdx, bucketOff, nb_t);

  k_scatter<<<(nt + 255) / 256, 256, 0, stream>>>((const int4*)tet, tetidx, bucketOff,
                                                  stash, edges32, stashAbs, nt);

  k_rankuniq<<<nb_rank, SB, 0, stream>>>(bucketOff, edges32, hrankArr, edgesU,
                                         uniqueCnt, tmpHead, scal, nv);

  long long maxidx = (long long)nt * 2;
  int N = (int)ceil(sqrt((double)((maxidx + 1) / 2)));
  int uvsElems = N * N * 8;

  k_i32scan1<<<nb_v, SB, 0, stream>>>(uniqueCnt, blockTotI, nv);
  k_uscanblk<<<1, SB, 0, stream>>>(blockTotI, nb_v, scal, uvsElems);
  k_i32scan3<<<nb_v, SB, 0, stream>>>(uniqueCnt, blockTotI, uniqueOff, nv);

  k_verts<<<nbv_verts, SB, 0, stream>>>(bucketOff, uniqueOff, hrankArr, edgesU, grank,
                                        pos, sdf, scal, (float*)d_out, nv);

  int faceBlocks = (nt + 255) / 256;
  int uvsBlocks = (N * N + 255) / 256;
  k_face<<<faceBlocks + uvsBlocks, 256, 0, stream>>>(tetidx, rowIdx, scal, stashAbs, grank,
                                                     (float*)d_out, nt, faceBlocks, N);
}